// Round 4
// baseline (133.856 us; speedup 1.0000x reference)
//
#include <hip/hip_runtime.h>
#include <stdint.h>

#define GN 4008      // reference GRID
#define RPC 8        // rows per chunk (power of 2: c = x>>3, xr = x&7)
#define CH 501       // x chunks; CH*RPC == GN
#define CPAD 4096    // padded column dim
#define OWS 128      // occ words per row
#define PW 128       // P16 words per row
#define YT 8         // y tiles in occ build
#define TW 512       // tile width; YT*TW == CPAD
#define RPADL 544    // TW + TW/16 padded LDS row
#define LOCCAP 1024
#define MAXPTS 8192
#define STRIP 126    // vscan strip length; 4 strips cover 501

static_assert(CH * RPC == GN, "chunking must cover grid");
static_assert(YT * TW == CPAD, "tiles must cover padded grid");

// ---------------- K1: corners -> Dcol scatter + chunk-bucketed point list --
// Single block (2000 boxes is tiny). JAX scatter semantics: negative index
// wraps (+GN), still-OOB (>=GN) update dropped.
__global__ __launch_bounds__(1024) void k_points(const float* __restrict__ gt, int ngt,
                                                 int* __restrict__ Dcol,
                                                 int* __restrict__ boff,
                                                 uint16_t* __restrict__ bpts,
                                                 double* __restrict__ acc) {
    __shared__ uint32_t plist[MAXPTS];
    __shared__ uint32_t bcnt[512];
    __shared__ uint32_t wcur[CH];
    __shared__ int wbase[64];
    __shared__ int npsh;
    int t = threadIdx.x;
    if (t < 512) bcnt[t] = 0;
    if (t == 0) { npsh = 0; *acc = 0.0; }
    __syncthreads();
    for (int i = t; i < ngt; i += 1024) {
        float4 b = ((const float4*)gt)[i];
        int x1 = (int)rintf(b.x * 100.0f);
        int y1 = (int)rintf(b.y * 100.0f);
        int x2 = (int)rintf(b.z * 100.0f);
        int y2 = (int)rintf(b.w * 100.0f);
        int xs[4] = {x1, x1, x2 + 1, x2 + 1};
        int ys[4] = {y1, y2 + 1, y1, y2 + 1};
        const int sgn[4] = {1, -1, -1, 1};
        #pragma unroll
        for (int q = 0; q < 4; ++q) {
            int x = xs[q], y = ys[q];
            if (x < 0) x += GN;
            if (y < 0) y += GN;
            if (x >= 0 && x < GN && y >= 0 && y < GN) {
                atomicAdd(&Dcol[(size_t)(x >> 3) * CPAD + y], sgn[q]);
                atomicAdd(&bcnt[x >> 3], 1u);
                int k = atomicAdd(&npsh, 1);
                uint32_t sb = (sgn[q] > 0) ? 1u : 0u;
                if (k < MAXPTS)
                    plist[k] = ((uint32_t)x << 13) | ((uint32_t)y << 1) | sb;
            }
        }
    }
    __syncthreads();
    int np = npsh; if (np > MAXPTS) np = MAXPTS;
    if (t < 64) {                 // wave 0: exclusive scan of 8-group sums
        int s = 0;
        #pragma unroll
        for (int k = 0; k < 8; ++k) s += (int)bcnt[t * 8 + k];
        int ss = s;
        #pragma unroll
        for (int d = 1; d < 64; d <<= 1) {
            int tmp = __shfl_up(ss, d);
            if (t >= d) ss += tmp;
        }
        wbase[t] = ss - s;
    }
    __syncthreads();
    for (int c = t; c < CH; c += 1024) {
        int e = wbase[c >> 3];
        for (int k = (c & ~7); k < c; ++k) e += (int)bcnt[k];
        boff[c] = e;
        wcur[c] = (uint32_t)e;
    }
    if (t == 0) boff[CH] = np;
    __syncthreads();
    for (int i = t; i < np; i += 1024) {
        uint32_t p = plist[i];
        int x = (int)(p >> 13);
        uint32_t pos = atomicAdd(&wcur[x >> 3], 1u);
        bpts[pos] = (uint16_t)((((uint32_t)x & 7u) << 13) | (p & 0x1FFFu));
    }
}

// ---------------- K2: horizontal inclusive scan of Dcol rows (in-place) ----
__global__ __launch_bounds__(256) void k_hscanD(int* __restrict__ D) {
    __shared__ int wsum[4];
    int c = blockIdx.x, t = threadIdx.x;
    int* row = D + (size_t)c * CPAD;
    int4* p = (int4*)(row + t * 16);
    int4 a0 = p[0], a1 = p[1], a2 = p[2], a3 = p[3];
    int in[16] = {a0.x, a0.y, a0.z, a0.w, a1.x, a1.y, a1.z, a1.w,
                  a2.x, a2.y, a2.z, a2.w, a3.x, a3.y, a3.z, a3.w};
    int v[16], s = 0;
    #pragma unroll
    for (int k = 0; k < 16; ++k) { s += in[k]; v[k] = s; }
    int lane = t & 63, wid = t >> 6;
    int ss = s;
    #pragma unroll
    for (int d = 1; d < 64; d <<= 1) {
        int tmp = __shfl_up(ss, d);
        if (lane >= d) ss += tmp;
    }
    if (lane == 63) wsum[wid] = ss;
    __syncthreads();
    int carry = ss - s;
    #pragma unroll
    for (int w = 0; w < 4; ++w) if (w < wid) carry += wsum[w];
    #pragma unroll
    for (int q = 0; q < 4; ++q)
        p[q] = make_int4(v[4 * q + 0] + carry, v[4 * q + 1] + carry,
                         v[4 * q + 2] + carry, v[4 * q + 3] + carry);
}

// ---------------- K3: vertical EXCLUSIVE scan over chunks (in-place) -------
// After this, Dcol buffer == Hpre[c][y] = count(8c-1, y).
__global__ __launch_bounds__(256) void k_vscanD(int* __restrict__ D) {
    __shared__ int ssum[4][64];
    int lj = threadIdx.x & 63;
    int col = blockIdx.x * 64 + lj;
    int s = threadIdx.x >> 6;
    int c0 = s * STRIP;
    int c1 = min(CH, c0 + STRIP);
    int sum = 0;
    for (int c = c0; c < c1; ++c) sum += D[(size_t)c * CPAD + col];
    ssum[s][lj] = sum;
    __syncthreads();
    int run = 0;
    for (int k = 0; k < s; ++k) run += ssum[k][lj];
    for (int c = c0; c < c1; ++c) {
        int tmp = D[(size_t)c * CPAD + col];
        D[(size_t)c * CPAD + col] = run;
        run += tmp;
    }
}

// ---------------- K4: occ build, one wave per (chunk, y-tile) --------------
__global__ __launch_bounds__(64) void k_occ(const uint16_t* __restrict__ bpts,
                                            const int* __restrict__ boff,
                                            const int* __restrict__ Hpre,
                                            uint32_t* __restrict__ occw,
                                            uint32_t* __restrict__ colsum32) {
    __shared__ int R[RPADL];
    __shared__ uint16_t loc[LOCCAP];
    __shared__ int carrD[RPC];
    __shared__ int nloc;
    int c = blockIdx.x;
    int tt = blockIdx.y;
    int r0 = c * RPC, y0 = tt * TW;
    int j = threadIdx.x;
    for (int i = j; i < RPADL; i += 64) R[i] = 0;
    if (j < RPC) carrD[j] = 0;
    if (j == 0) nloc = 0;
    __syncthreads();
    int b0 = boff[c], b1 = boff[c + 1];
    for (int i = b0 + j; i < b1; i += 64) {
        uint32_t e = bpts[i];
        int py = (int)((e >> 1) & 0xFFFu);
        int xr = (int)(e >> 13);
        int ry = py - y0;
        if (ry >= 0 && ry < TW) {
            int k = atomicAdd(&nloc, 1);
            if (k < LOCCAP)
                loc[k] = (uint16_t)((xr << 10) | (ry << 1) | (e & 1u));
        } else if (ry < 0) {
            atomicAdd(&carrD[xr], (e & 1u) ? 1 : -1);
        }
    }
    const int4* hp = (const int4*)(Hpre + (size_t)c * CPAD + y0 + j * 8);
    int4 h0 = hp[0], h1 = hp[1];
    int h[8] = {h0.x, h0.y, h0.z, h0.w, h1.x, h1.y, h1.z, h1.w};
    __syncthreads();
    bool ovf = (nloc > LOCCAP);
    int nl = ovf ? 0 : nloc;
    uint32_t cnt[8] = {0, 0, 0, 0, 0, 0, 0, 0};
    int cb = 0;
    int base = j * 8;
    for (int xr = 0; xr < RPC; ++xr) {
        if (!ovf) {
            for (int i = j; i < nl; i += 64) {
                uint32_t e = loc[i];
                if ((int)(e >> 10) == xr) {
                    int ry = (int)((e >> 1) & 0x1FFu);
                    atomicAdd(&R[ry + (ry >> 4)], (e & 1u) ? 1 : -1);
                }
            }
        } else {                 // correctness fallback: rescan this bucket
            for (int i = b0 + j; i < b1; i += 64) {
                uint32_t e = bpts[i];
                if ((int)(e >> 13) == xr) {
                    int ry = (int)((e >> 1) & 0xFFFu) - y0;
                    if (ry >= 0 && ry < TW)
                        atomicAdd(&R[ry + (ry >> 4)], (e & 1u) ? 1 : -1);
                }
            }
        }
        __syncthreads();
        cb += carrD[xr];
        int v[8], sl = 0;
        #pragma unroll
        for (int k = 0; k < 8; ++k) {
            int a = base + k;
            sl += R[a + (a >> 4)];
            v[k] = sl;
        }
        int ss = sl;
        #pragma unroll
        for (int d = 1; d < 64; d <<= 1) {
            int tmp = __shfl_up(ss, d);
            if (j >= d) ss += tmp;
        }
        int excl = ss - sl + cb;
        uint32_t m = 0;
        #pragma unroll
        for (int k = 0; k < 8; ++k) {
            int gy = y0 + base + k;
            if (gy < GN && (h[k] + excl + v[k]) > 0) m |= (1u << k);
        }
        #pragma unroll
        for (int k = 0; k < 8; ++k) cnt[k] += (m >> k) & 1u;
        uint32_t w = m << (8 * (j & 3));
        w |= __shfl_xor(w, 1);
        w |= __shfl_xor(w, 2);
        if ((j & 3) == 0)
            occw[(size_t)(r0 + xr) * OWS + tt * 16 + (j >> 2)] = w;
        __syncthreads();
    }
    uint4 cw;
    cw.x = cnt[0] | (cnt[1] << 16);
    cw.y = cnt[2] | (cnt[3] << 16);
    cw.z = cnt[4] | (cnt[5] << 16);
    cw.w = cnt[6] | (cnt[7] << 16);
    *(uint4*)(colsum32 + (((size_t)c * CPAD + y0 + base) >> 1)) = cw;
}

// ---------------- K5 fused: P16 (blocks 0..1001) + vscanC (1002..1033) -----
#define P16BLKS 1002
__global__ __launch_bounds__(256) void k_p16_vscanC(const uint32_t* __restrict__ occw,
                                                    uint32_t* __restrict__ P16_32,
                                                    const uint32_t* __restrict__ colsum32,
                                                    uint32_t* __restrict__ Vc32) {
    __shared__ uint32_t ssum[4][64];
    int blk = blockIdx.x;
    int lj = threadIdx.x & 63;
    int wid = threadIdx.x >> 6;
    if (blk < P16BLKS) {
        int x = blk * 4 + wid;
        uint2 w = ((const uint2*)(occw + (size_t)x * OWS))[lj];
        int p0 = __popc(w.x), p1 = __popc(w.y);
        int tot = p0 + p1;
        int ss = tot;
        #pragma unroll
        for (int d = 1; d < 64; d <<= 1) {
            int tmp = __shfl_up(ss, d);
            if (lj >= d) ss += tmp;
        }
        int excl = ss - tot;
        P16_32[(size_t)x * (PW / 2) + lj] = (uint32_t)excl | ((uint32_t)(excl + p0) << 16);
    } else {
        int wc = (blk - P16BLKS) * 64 + lj;
        int c0 = wid * STRIP;
        int c1 = min(CH, c0 + STRIP);
        uint32_t sum = 0;
        for (int c = c0; c < c1; ++c) sum += colsum32[(size_t)c * (CPAD / 2) + wc];
        ssum[wid][lj] = sum;
        __syncthreads();
        uint32_t run = 0;
        for (int k = 0; k < wid; ++k) run += ssum[k][lj];
        for (int c = c0; c < c1; ++c) {
            Vc32[(size_t)c * (CPAD / 2) + wc] = run;
            run += colsum32[(size_t)c * (CPAD / 2) + wc];
        }
        if (c1 == CH) Vc32[(size_t)CH * (CPAD / 2) + wc] = run;
    }
}

// ---------------- K6: horizontal inclusive scan of Vc rows -> Ic -----------
__global__ __launch_bounds__(256) void k_hscanC(const uint16_t* __restrict__ Vc,
                                                int* __restrict__ Ic) {
    __shared__ int wsum[4];
    int c = blockIdx.x, t = threadIdx.x;
    const uint32_t* row = (const uint32_t*)(Vc + (size_t)c * CPAD);
    const int4* p = (const int4*)(row + (size_t)t * 8);
    int4 A = p[0];
    int4 B = p[1];
    uint32_t w[8] = {(uint32_t)A.x, (uint32_t)A.y, (uint32_t)A.z, (uint32_t)A.w,
                     (uint32_t)B.x, (uint32_t)B.y, (uint32_t)B.z, (uint32_t)B.w};
    int v[16], s = 0;
    #pragma unroll
    for (int q = 0; q < 8; ++q) {
        s += (int)(w[q] & 0xFFFFu); v[2 * q] = s;
        s += (int)(w[q] >> 16);     v[2 * q + 1] = s;
    }
    int lane = t & 63, wid = t >> 6;
    int ss = s;
    #pragma unroll
    for (int d = 1; d < 64; d <<= 1) {
        int tmp = __shfl_up(ss, d);
        if (lane >= d) ss += tmp;
    }
    if (lane == 63) wsum[wid] = ss;
    __syncthreads();
    int carry = ss - s;
    #pragma unroll
    for (int w2 = 0; w2 < 4; ++w2) if (w2 < wid) carry += wsum[w2];
    int4* o = (int4*)(Ic + (size_t)c * CPAD + (size_t)t * 16);
    #pragma unroll
    for (int q = 0; q < 4; ++q)
        o[q] = make_int4(v[4 * q + 0] + carry, v[4 * q + 1] + carry,
                         v[4 * q + 2] + carry, v[4 * q + 3] + carry);
}

// ---------------- K7: gather (one thread per box-corner) + reduce ----------
__device__ __forceinline__ int clampI(int a) {
    return a < 0 ? 0 : (a > GN ? GN : a);
}

__global__ __launch_bounds__(256) void k_gather(const float* __restrict__ pred, int npred,
                                                const int* __restrict__ Ic,
                                                const uint16_t* __restrict__ P16,
                                                const uint32_t* __restrict__ occw,
                                                double* __restrict__ acc) {
    __shared__ double red[4];
    int g = blockIdx.x * 256 + threadIdx.x;
    int i = g >> 2, k = g & 3;
    double l = 0.0;
    int x1 = 0, y1 = 0, x2 = 0, y2 = 0;
    int cov = 0;
    if (i < npred) {
        float4 bx = ((const float4*)pred)[i];
        x1 = (int)rintf(bx.x * 100.0f);
        y1 = (int)rintf(bx.y * 100.0f);
        x2 = (int)rintf(bx.z * 100.0f);
        y2 = (int)rintf(bx.w * 100.0f);
        int a1 = clampI(x1), b1 = clampI(y1), a2 = clampI(x2), b2 = clampI(y2);
        int a = (k & 1) ? a1 : a2;
        int b = (k & 2) ? b1 : b2;
        int sgn = ((k ^ (k >> 1)) & 1) ? -1 : 1;
        int Iv = 0;
        if (a > 0 && b > 0) {
            int c = a >> 3;
            Iv = Ic[(size_t)c * CPAD + (b - 1)];
            int bw = b >> 5;
            uint32_t mask = (1u << (b & 31)) - 1u;   // b&31==0 -> 0
            for (int x = (a & ~7); x < a; ++x)
                Iv += (int)P16[(size_t)x * PW + bw] + __popc(occw[(size_t)x * OWS + bw] & mask);
        }
        cov = sgn * Iv;
    }
    cov += __shfl_xor(cov, 1);
    cov += __shfl_xor(cov, 2);
    if (i < npred && k == 0) {
        int area = (x2 - x1) * (y2 - y1);
        bool valid = (x2 > x1) && (y2 > y1);
        float iou = valid ? ((float)cov / fmaxf((float)area, 1.0f)) : 0.0f;
        l = (double)(1.0f - iou);
    }
    #pragma unroll
    for (int d = 32; d > 0; d >>= 1) l += __shfl_down(l, d);
    int lane = threadIdx.x & 63, wid = threadIdx.x >> 6;
    if (lane == 0) red[wid] = l;
    __syncthreads();
    if (threadIdx.x == 0)
        atomicAdd(acc, red[0] + red[1] + red[2] + red[3]);
}

// ---------------- K8: finalize ---------------------------------------------
__global__ void k_final(const double* __restrict__ acc, float* __restrict__ out, int npred) {
    out[0] = (float)(*acc / (double)npred);
}

extern "C" void kernel_launch(void* const* d_in, const int* in_sizes, int n_in,
                              void* d_out, int out_size, void* d_ws, size_t ws_size,
                              hipStream_t stream) {
    const float* pred = (const float*)d_in[0];
    // d_in[1] = target, unused by the reference loss
    const float* gt = (const float*)d_in[2];
    int npred = in_sizes[0] / 4;
    int ngt = in_sizes[2] / 4;

    char* ws = (char*)d_ws;
    size_t off = 0;
    auto alloc = [&](size_t bytes) {
        void* p = ws + off;
        off = (off + bytes + 255) & ~(size_t)255;
        return p;
    };
    int* Dcol = (int*)alloc((size_t)CH * CPAD * sizeof(int));                 // 8.2 MB; becomes Hpre
    int* Ic = (int*)alloc((size_t)(CH + 1) * CPAD * sizeof(int));             // 8.2 MB
    uint32_t* occw = (uint32_t*)alloc((size_t)GN * OWS * sizeof(uint32_t));   // 2.05 MB
    uint16_t* P16 = (uint16_t*)alloc((size_t)GN * PW * sizeof(uint16_t));     // 1.03 MB
    uint16_t* colsum = (uint16_t*)alloc((size_t)CH * CPAD * sizeof(uint16_t)); // 4.1 MB
    uint16_t* Vc = (uint16_t*)alloc((size_t)(CH + 1) * CPAD * sizeof(uint16_t)); // 4.1 MB
    uint16_t* bpts = (uint16_t*)alloc((size_t)MAXPTS * sizeof(uint16_t));
    int* boff = (int*)alloc((size_t)(CH + 1) * sizeof(int));
    double* acc = (double*)alloc(sizeof(double));

    hipMemsetAsync(Dcol, 0, (size_t)CH * CPAD * sizeof(int), stream);
    k_points<<<dim3(1), dim3(1024), 0, stream>>>(gt, ngt, Dcol, boff, bpts, acc);
    k_hscanD<<<dim3(CH), dim3(256), 0, stream>>>(Dcol);
    k_vscanD<<<dim3(CPAD / 64), dim3(256), 0, stream>>>(Dcol);
    k_occ<<<dim3(CH, YT), dim3(64), 0, stream>>>(bpts, boff, Dcol, occw, (uint32_t*)colsum);
    k_p16_vscanC<<<dim3(P16BLKS + 32), dim3(256), 0, stream>>>(occw, (uint32_t*)P16,
                                                               (const uint32_t*)colsum, (uint32_t*)Vc);
    k_hscanC<<<dim3(CH + 1), dim3(256), 0, stream>>>(Vc, Ic);
    k_gather<<<dim3((4 * npred + 255) / 256), dim3(256), 0, stream>>>(pred, npred, Ic, P16, occw, acc);
    k_final<<<1, 1, 0, stream>>>(acc, (float*)d_out, npred);
}

// Round 5
// 101.189 us; speedup vs baseline: 1.3228x; 1.3228x over previous
//
#include <hip/hip_runtime.h>
#include <stdint.h>

#define GN 4008      // reference GRID
#define RPC 8        // rows per chunk (power of 2: c = x>>3, xr = x&7)
#define CH 501       // x chunks; CH*RPC == GN
#define CPAD 4096    // padded column dim
#define OWS 128      // occ words per row
#define PW 128       // PO words per row
#define YT 8         // y tiles in occ build
#define TW 512       // tile width; YT*TW == CPAD
#define RPADL 544    // TW + TW/16 padded LDS row
#define HPAD 4352    // CPAD + CPAD/16 padded LDS histogram
#define LOCCAP 1024
#define MAXPTS 8192
#define STRIP 126    // colsum vscan strip length; 4 strips cover 501
#define VSTRIP 63    // Dcol vscan strip length; 8 strips cover 501

static_assert(CH * RPC == GN, "chunking must cover grid");
static_assert(YT * TW == CPAD, "tiles must cover padded grid");

// ---------------- K1: corners -> chunk-bucketed point list -----------------
// Single block. JAX scatter semantics: negative index wraps (+GN), still-OOB
// (>=GN) update dropped.
__global__ __launch_bounds__(1024) void k_points(const float* __restrict__ gt, int ngt,
                                                 int* __restrict__ boff,
                                                 uint16_t* __restrict__ bpts,
                                                 double* __restrict__ acc,
                                                 int* __restrict__ done) {
    __shared__ uint32_t plist[MAXPTS];
    __shared__ uint32_t bcnt[512];
    __shared__ uint32_t wcur[CH];
    __shared__ int wbase[64];
    __shared__ int npsh;
    int t = threadIdx.x;
    if (t < 512) bcnt[t] = 0;
    if (t == 0) { npsh = 0; *acc = 0.0; *done = 0; }
    __syncthreads();
    for (int i = t; i < ngt; i += 1024) {
        float4 b = ((const float4*)gt)[i];
        int x1 = (int)rintf(b.x * 100.0f);
        int y1 = (int)rintf(b.y * 100.0f);
        int x2 = (int)rintf(b.z * 100.0f);
        int y2 = (int)rintf(b.w * 100.0f);
        int xs[4] = {x1, x1, x2 + 1, x2 + 1};
        int ys[4] = {y1, y2 + 1, y1, y2 + 1};
        const int sgn[4] = {1, -1, -1, 1};
        #pragma unroll
        for (int q = 0; q < 4; ++q) {
            int x = xs[q], y = ys[q];
            if (x < 0) x += GN;
            if (y < 0) y += GN;
            if (x >= 0 && x < GN && y >= 0 && y < GN) {
                atomicAdd(&bcnt[x >> 3], 1u);
                int k = atomicAdd(&npsh, 1);
                uint32_t sb = (sgn[q] > 0) ? 1u : 0u;
                if (k < MAXPTS)
                    plist[k] = ((uint32_t)x << 13) | ((uint32_t)y << 1) | sb;
            }
        }
    }
    __syncthreads();
    int np = npsh; if (np > MAXPTS) np = MAXPTS;
    if (t < 64) {                 // wave 0: exclusive scan of 8-group sums
        int s = 0;
        #pragma unroll
        for (int k = 0; k < 8; ++k) s += (int)bcnt[t * 8 + k];
        int ss = s;
        #pragma unroll
        for (int d = 1; d < 64; d <<= 1) {
            int tmp = __shfl_up(ss, d);
            if (t >= d) ss += tmp;
        }
        wbase[t] = ss - s;
    }
    __syncthreads();
    for (int c = t; c < CH; c += 1024) {
        int e = wbase[c >> 3];
        for (int k = (c & ~7); k < c; ++k) e += (int)bcnt[k];
        boff[c] = e;
        wcur[c] = (uint32_t)e;
    }
    if (t == 0) boff[CH] = np;
    __syncthreads();
    for (int i = t; i < np; i += 1024) {
        uint32_t p = plist[i];
        int x = (int)(p >> 13);
        uint32_t pos = atomicAdd(&wcur[x >> 3], 1u);
        bpts[pos] = (uint16_t)((((uint32_t)x & 7u) << 13) | (p & 0x1FFFu));
    }
}

// ---------------- K2: per-chunk column histogram + h-scan -> Dcol row ------
// Replaces {memset + global scatter + hscanD}: builds the chunk's column
// delta histogram in LDS from its bucket, h-scans it, writes the row.
__global__ __launch_bounds__(256) void k_hrow(const uint16_t* __restrict__ bpts,
                                              const int* __restrict__ boff,
                                              int* __restrict__ Dcol) {
    __shared__ int H[HPAD];
    __shared__ int wsum[4];
    int c = blockIdx.x, t = threadIdx.x;
    for (int i = t; i < HPAD; i += 256) H[i] = 0;
    __syncthreads();
    int b0 = boff[c], b1 = boff[c + 1];
    for (int i = b0 + t; i < b1; i += 256) {
        uint32_t e = bpts[i];
        int y = (int)((e >> 1) & 0xFFFu);
        atomicAdd(&H[y + (y >> 4)], (e & 1u) ? 1 : -1);
    }
    __syncthreads();
    int base = t * 16;
    int v[16], s = 0;
    #pragma unroll
    for (int j = 0; j < 16; ++j) { s += H[17 * t + j]; v[j] = s; }
    int lane = t & 63, wid = t >> 6;
    int ss = s;
    #pragma unroll
    for (int d = 1; d < 64; d <<= 1) {
        int tmp = __shfl_up(ss, d);
        if (lane >= d) ss += tmp;
    }
    if (lane == 63) wsum[wid] = ss;
    __syncthreads();
    int carry = ss - s;
    #pragma unroll
    for (int w = 0; w < 4; ++w) if (w < wid) carry += wsum[w];
    int4* o = (int4*)(Dcol + (size_t)c * CPAD + base);
    #pragma unroll
    for (int q = 0; q < 4; ++q)
        o[q] = make_int4(v[4 * q + 0] + carry, v[4 * q + 1] + carry,
                         v[4 * q + 2] + carry, v[4 * q + 3] + carry);
}

// ---------------- K3: vertical EXCLUSIVE scan over chunks (in-place) -------
// After this, Dcol buffer == Hpre[c][y] = count(8c-1, y).
__global__ __launch_bounds__(512) void k_vscanD(int* __restrict__ D) {
    __shared__ int ssum[8][64];
    int lj = threadIdx.x & 63;
    int col = blockIdx.x * 64 + lj;
    int s = threadIdx.x >> 6;          // strip 0..7
    int c0 = s * VSTRIP;
    int c1 = min(CH, c0 + VSTRIP);
    int sum = 0;
    for (int c = c0; c < c1; ++c) sum += D[(size_t)c * CPAD + col];
    ssum[s][lj] = sum;
    __syncthreads();
    int run = 0;
    for (int k = 0; k < s; ++k) run += ssum[k][lj];
    for (int c = c0; c < c1; ++c) {
        int tmp = D[(size_t)c * CPAD + col];
        D[(size_t)c * CPAD + col] = run;
        run += tmp;
    }
}

// ---------------- K4: occ build, one wave per (chunk, y-tile) --------------
__global__ __launch_bounds__(64) void k_occ(const uint16_t* __restrict__ bpts,
                                            const int* __restrict__ boff,
                                            const int* __restrict__ Hpre,
                                            uint32_t* __restrict__ occw,
                                            uint32_t* __restrict__ colsum32) {
    __shared__ int R[RPADL];
    __shared__ uint16_t loc[LOCCAP];
    __shared__ int carrD[RPC];
    __shared__ int nloc;
    int c = blockIdx.x;
    int tt = blockIdx.y;
    int r0 = c * RPC, y0 = tt * TW;
    int j = threadIdx.x;
    for (int i = j; i < RPADL; i += 64) R[i] = 0;
    if (j < RPC) carrD[j] = 0;
    if (j == 0) nloc = 0;
    __syncthreads();
    int b0 = boff[c], b1 = boff[c + 1];
    for (int i = b0 + j; i < b1; i += 64) {
        uint32_t e = bpts[i];
        int py = (int)((e >> 1) & 0xFFFu);
        int xr = (int)(e >> 13);
        int ry = py - y0;
        if (ry >= 0 && ry < TW) {
            int k = atomicAdd(&nloc, 1);
            if (k < LOCCAP)
                loc[k] = (uint16_t)((xr << 10) | (ry << 1) | (e & 1u));
        } else if (ry < 0) {
            atomicAdd(&carrD[xr], (e & 1u) ? 1 : -1);
        }
    }
    const int4* hp = (const int4*)(Hpre + (size_t)c * CPAD + y0 + j * 8);
    int4 h0 = hp[0], h1 = hp[1];
    int h[8] = {h0.x, h0.y, h0.z, h0.w, h1.x, h1.y, h1.z, h1.w};
    __syncthreads();
    bool ovf = (nloc > LOCCAP);
    int nl = ovf ? 0 : nloc;
    uint32_t cnt[8] = {0, 0, 0, 0, 0, 0, 0, 0};
    int cb = 0;
    int base = j * 8;
    for (int xr = 0; xr < RPC; ++xr) {
        if (!ovf) {
            for (int i = j; i < nl; i += 64) {
                uint32_t e = loc[i];
                if ((int)(e >> 10) == xr) {
                    int ry = (int)((e >> 1) & 0x1FFu);
                    atomicAdd(&R[ry + (ry >> 4)], (e & 1u) ? 1 : -1);
                }
            }
        } else {                 // correctness fallback: rescan this bucket
            for (int i = b0 + j; i < b1; i += 64) {
                uint32_t e = bpts[i];
                if ((int)(e >> 13) == xr) {
                    int ry = (int)((e >> 1) & 0xFFFu) - y0;
                    if (ry >= 0 && ry < TW)
                        atomicAdd(&R[ry + (ry >> 4)], (e & 1u) ? 1 : -1);
                }
            }
        }
        __syncthreads();
        cb += carrD[xr];
        int v[8], sl = 0;
        #pragma unroll
        for (int k = 0; k < 8; ++k) {
            int a = base + k;
            sl += R[a + (a >> 4)];
            v[k] = sl;
        }
        int ss = sl;
        #pragma unroll
        for (int d = 1; d < 64; d <<= 1) {
            int tmp = __shfl_up(ss, d);
            if (j >= d) ss += tmp;
        }
        int excl = ss - sl + cb;
        uint32_t m = 0;
        #pragma unroll
        for (int k = 0; k < 8; ++k) {
            int gy = y0 + base + k;
            if (gy < GN && (h[k] + excl + v[k]) > 0) m |= (1u << k);
        }
        #pragma unroll
        for (int k = 0; k < 8; ++k) cnt[k] += (m >> k) & 1u;
        uint32_t w = m << (8 * (j & 3));
        w |= __shfl_xor(w, 1);
        w |= __shfl_xor(w, 2);
        if ((j & 3) == 0)
            occw[(size_t)(r0 + xr) * OWS + tt * 16 + (j >> 2)] = w;
        __syncthreads();
    }
    uint4 cw;
    cw.x = cnt[0] | (cnt[1] << 16);
    cw.y = cnt[2] | (cnt[3] << 16);
    cw.z = cnt[4] | (cnt[5] << 16);
    cw.w = cnt[6] | (cnt[7] << 16);
    *(uint4*)(colsum32 + (((size_t)c * CPAD + y0 + base) >> 1)) = cw;
}

// ---------------- K5 fused: PO build (blocks 0..1001) + vscanC (1002..) ----
// PO[x][w] = occ word | (exclusive word-popcount prefix << 48).
#define P16BLKS 1002
__global__ __launch_bounds__(256) void k_po_vscanC(const uint32_t* __restrict__ occw,
                                                   uint64_t* __restrict__ PO,
                                                   const uint32_t* __restrict__ colsum32,
                                                   uint32_t* __restrict__ Vc32) {
    __shared__ uint32_t ssum[4][64];
    int blk = blockIdx.x;
    int lj = threadIdx.x & 63;
    int wid = threadIdx.x >> 6;
    if (blk < P16BLKS) {
        int x = blk * 4 + wid;
        uint2 w = ((const uint2*)(occw + (size_t)x * OWS))[lj];
        int p0 = __popc(w.x), p1 = __popc(w.y);
        int tot = p0 + p1;
        int ss = tot;
        #pragma unroll
        for (int d = 1; d < 64; d <<= 1) {
            int tmp = __shfl_up(ss, d);
            if (lj >= d) ss += tmp;
        }
        int excl = ss - tot;
        ulonglong2 o;
        o.x = (uint64_t)w.x | ((uint64_t)(uint32_t)excl << 48);
        o.y = (uint64_t)w.y | ((uint64_t)(uint32_t)(excl + p0) << 48);
        ((ulonglong2*)(PO + (size_t)x * PW))[lj] = o;
    } else {
        int wc = (blk - P16BLKS) * 64 + lj;
        int c0 = wid * STRIP;
        int c1 = min(CH, c0 + STRIP);
        uint32_t sum = 0;
        for (int c = c0; c < c1; ++c) sum += colsum32[(size_t)c * (CPAD / 2) + wc];
        ssum[wid][lj] = sum;
        __syncthreads();
        uint32_t run = 0;
        for (int k = 0; k < wid; ++k) run += ssum[k][lj];
        for (int c = c0; c < c1; ++c) {
            Vc32[(size_t)c * (CPAD / 2) + wc] = run;
            run += colsum32[(size_t)c * (CPAD / 2) + wc];
        }
        if (c1 == CH) Vc32[(size_t)CH * (CPAD / 2) + wc] = run;
    }
}

// ---------------- K6: horizontal inclusive scan of Vc rows -> Ic -----------
__global__ __launch_bounds__(256) void k_hscanC(const uint16_t* __restrict__ Vc,
                                                int* __restrict__ Ic) {
    __shared__ int wsum[4];
    int c = blockIdx.x, t = threadIdx.x;
    const uint32_t* row = (const uint32_t*)(Vc + (size_t)c * CPAD);
    const int4* p = (const int4*)(row + (size_t)t * 8);
    int4 A = p[0];
    int4 B = p[1];
    uint32_t w[8] = {(uint32_t)A.x, (uint32_t)A.y, (uint32_t)A.z, (uint32_t)A.w,
                     (uint32_t)B.x, (uint32_t)B.y, (uint32_t)B.z, (uint32_t)B.w};
    int v[16], s = 0;
    #pragma unroll
    for (int q = 0; q < 8; ++q) {
        s += (int)(w[q] & 0xFFFFu); v[2 * q] = s;
        s += (int)(w[q] >> 16);     v[2 * q + 1] = s;
    }
    int lane = t & 63, wid = t >> 6;
    int ss = s;
    #pragma unroll
    for (int d = 1; d < 64; d <<= 1) {
        int tmp = __shfl_up(ss, d);
        if (lane >= d) ss += tmp;
    }
    if (lane == 63) wsum[wid] = ss;
    __syncthreads();
    int carry = ss - s;
    #pragma unroll
    for (int w2 = 0; w2 < 4; ++w2) if (w2 < wid) carry += wsum[w2];
    int4* o = (int4*)(Ic + (size_t)c * CPAD + (size_t)t * 16);
    #pragma unroll
    for (int q = 0; q < 4; ++q)
        o[q] = make_int4(v[4 * q + 0] + carry, v[4 * q + 1] + carry,
                         v[4 * q + 2] + carry, v[4 * q + 3] + carry);
}

// ---------------- K7: gather (thread per box-corner) + reduce + finalize ---
__device__ __forceinline__ int clampI(int a) {
    return a < 0 ? 0 : (a > GN ? GN : a);
}

__global__ __launch_bounds__(256) void k_gather(const float* __restrict__ pred, int npred,
                                                const int* __restrict__ Ic,
                                                const uint64_t* __restrict__ PO,
                                                double* __restrict__ acc,
                                                int* __restrict__ done,
                                                float* __restrict__ out, int nblocks) {
    __shared__ double red[4];
    int g = blockIdx.x * 256 + threadIdx.x;
    int i = g >> 2, k = g & 3;
    double l = 0.0;
    int x1 = 0, y1 = 0, x2 = 0, y2 = 0;
    int cov = 0;
    if (i < npred) {
        float4 bx = ((const float4*)pred)[i];
        x1 = (int)rintf(bx.x * 100.0f);
        y1 = (int)rintf(bx.y * 100.0f);
        x2 = (int)rintf(bx.z * 100.0f);
        y2 = (int)rintf(bx.w * 100.0f);
        int a1 = clampI(x1), b1 = clampI(y1), a2 = clampI(x2), b2 = clampI(y2);
        int a = (k & 1) ? a1 : a2;
        int b = (k & 2) ? b1 : b2;
        int sgn = ((k ^ (k >> 1)) & 1) ? -1 : 1;
        int Iv = 0;
        if (a > 0 && b > 0) {
            int c = a >> 3;
            Iv = Ic[(size_t)c * CPAD + (b - 1)];
            int bw = b >> 5;
            uint32_t mask = (1u << (b & 31)) - 1u;   // b&31==0 -> 0
            for (int x = (a & ~7); x < a; ++x) {
                uint64_t po = PO[(size_t)x * PW + bw];
                Iv += (int)(po >> 48) + __popc((uint32_t)po & mask);
            }
        }
        cov = sgn * Iv;
    }
    cov += __shfl_xor(cov, 1);
    cov += __shfl_xor(cov, 2);
    if (i < npred && k == 0) {
        int area = (x2 - x1) * (y2 - y1);
        bool valid = (x2 > x1) && (y2 > y1);
        float iou = valid ? ((float)cov / fmaxf((float)area, 1.0f)) : 0.0f;
        l = (double)(1.0f - iou);
    }
    #pragma unroll
    for (int d = 32; d > 0; d >>= 1) l += __shfl_down(l, d);
    int lane = threadIdx.x & 63, wid = threadIdx.x >> 6;
    if (lane == 0) red[wid] = l;
    __syncthreads();
    if (threadIdx.x == 0) {
        atomicAdd(acc, red[0] + red[1] + red[2] + red[3]);
        __threadfence();
        if (atomicAdd(done, 1) == nblocks - 1) {
            double total = atomicAdd(acc, 0.0);   // coherent read of final sum
            out[0] = (float)(total / (double)npred);
        }
    }
}

extern "C" void kernel_launch(void* const* d_in, const int* in_sizes, int n_in,
                              void* d_out, int out_size, void* d_ws, size_t ws_size,
                              hipStream_t stream) {
    const float* pred = (const float*)d_in[0];
    // d_in[1] = target, unused by the reference loss
    const float* gt = (const float*)d_in[2];
    int npred = in_sizes[0] / 4;
    int ngt = in_sizes[2] / 4;

    char* ws = (char*)d_ws;
    size_t off = 0;
    auto alloc = [&](size_t bytes) {
        void* p = ws + off;
        off = (off + bytes + 255) & ~(size_t)255;
        return p;
    };
    int* Dcol = (int*)alloc((size_t)CH * CPAD * sizeof(int));                  // 8.2 MB; becomes Hpre
    int* Ic = (int*)alloc((size_t)(CH + 1) * CPAD * sizeof(int));              // 8.2 MB
    uint32_t* occw = (uint32_t*)alloc((size_t)GN * OWS * sizeof(uint32_t));    // 2.05 MB
    uint64_t* PO = (uint64_t*)alloc((size_t)GN * PW * sizeof(uint64_t));       // 4.1 MB
    uint16_t* colsum = (uint16_t*)alloc((size_t)CH * CPAD * sizeof(uint16_t)); // 4.1 MB
    uint16_t* Vc = (uint16_t*)alloc((size_t)(CH + 1) * CPAD * sizeof(uint16_t)); // 4.1 MB
    uint16_t* bpts = (uint16_t*)alloc((size_t)MAXPTS * sizeof(uint16_t));
    int* boff = (int*)alloc((size_t)(CH + 1) * sizeof(int));
    double* acc = (double*)alloc(sizeof(double));
    int* done = (int*)alloc(sizeof(int));

    int nb = (4 * npred + 255) / 256;
    k_points<<<dim3(1), dim3(1024), 0, stream>>>(gt, ngt, boff, bpts, acc, done);
    k_hrow<<<dim3(CH), dim3(256), 0, stream>>>(bpts, boff, Dcol);
    k_vscanD<<<dim3(CPAD / 64), dim3(512), 0, stream>>>(Dcol);
    k_occ<<<dim3(CH, YT), dim3(64), 0, stream>>>(bpts, boff, Dcol, occw, (uint32_t*)colsum);
    k_po_vscanC<<<dim3(P16BLKS + 32), dim3(256), 0, stream>>>(occw, PO,
                                                              (const uint32_t*)colsum, (uint32_t*)Vc);
    k_hscanC<<<dim3(CH + 1), dim3(256), 0, stream>>>(Vc, Ic);
    k_gather<<<dim3(nb), dim3(256), 0, stream>>>(pred, npred, Ic, PO, acc, done,
                                                 (float*)d_out, nb);
}

// Round 6
// 75.260 us; speedup vs baseline: 1.7786x; 1.3445x over previous
//
#include <hip/hip_runtime.h>
#include <stdint.h>

#define GN 4008      // reference GRID
#define RPC 8        // rows per chunk (power of 2: c = x>>3, xr = x&7)
#define CH 501       // x chunks; CH*RPC == GN
#define CPAD 4096    // padded column dim
#define OWS 128      // occ words per row
#define PW 128       // PO words per row
#define YT 8         // y tiles in occ build
#define TW 512       // tile width; YT*TW == CPAD
#define RPADL 544    // TW + TW/16 padded LDS row
#define HPAD 4352    // CPAD + CPAD/16 padded LDS histogram
#define LOCCAP 1024
#define MAXPTS 8192
#define NSTRIP 32    // strips for vertical scans
#define SSTR 16      // chunks per strip; 32*16=512 >= 501

static_assert(CH * RPC == GN, "chunking must cover grid");
static_assert(YT * TW == CPAD, "tiles must cover padded grid");
static_assert(NSTRIP * SSTR >= CH, "strips must cover chunks");

// ---------------- K1: corners -> chunk-bucketed point list -----------------
// Single block. JAX scatter semantics: negative index wraps (+GN), still-OOB
// (>=GN) update dropped.
__global__ __launch_bounds__(1024) void k_points(const float* __restrict__ gt, int ngt,
                                                 int* __restrict__ boff,
                                                 uint16_t* __restrict__ bpts,
                                                 double* __restrict__ acc,
                                                 int* __restrict__ done) {
    __shared__ uint32_t plist[MAXPTS];
    __shared__ uint32_t bcnt[512];
    __shared__ uint32_t wcur[CH];
    __shared__ int wbase[64];
    __shared__ int npsh;
    int t = threadIdx.x;
    if (t < 512) bcnt[t] = 0;
    if (t == 0) { npsh = 0; *acc = 0.0; *done = 0; }
    __syncthreads();
    for (int i = t; i < ngt; i += 1024) {
        float4 b = ((const float4*)gt)[i];
        int x1 = (int)rintf(b.x * 100.0f);
        int y1 = (int)rintf(b.y * 100.0f);
        int x2 = (int)rintf(b.z * 100.0f);
        int y2 = (int)rintf(b.w * 100.0f);
        int xs[4] = {x1, x1, x2 + 1, x2 + 1};
        int ys[4] = {y1, y2 + 1, y1, y2 + 1};
        const int sgn[4] = {1, -1, -1, 1};
        #pragma unroll
        for (int q = 0; q < 4; ++q) {
            int x = xs[q], y = ys[q];
            if (x < 0) x += GN;
            if (y < 0) y += GN;
            if (x >= 0 && x < GN && y >= 0 && y < GN) {
                atomicAdd(&bcnt[x >> 3], 1u);
                int k = atomicAdd(&npsh, 1);
                uint32_t sb = (sgn[q] > 0) ? 1u : 0u;
                if (k < MAXPTS)
                    plist[k] = ((uint32_t)x << 13) | ((uint32_t)y << 1) | sb;
            }
        }
    }
    __syncthreads();
    int np = npsh; if (np > MAXPTS) np = MAXPTS;
    if (t < 64) {                 // wave 0: exclusive scan of 8-group sums
        int s = 0;
        #pragma unroll
        for (int k = 0; k < 8; ++k) s += (int)bcnt[t * 8 + k];
        int ss = s;
        #pragma unroll
        for (int d = 1; d < 64; d <<= 1) {
            int tmp = __shfl_up(ss, d);
            if (t >= d) ss += tmp;
        }
        wbase[t] = ss - s;
    }
    __syncthreads();
    for (int c = t; c < CH; c += 1024) {
        int e = wbase[c >> 3];
        for (int k = (c & ~7); k < c; ++k) e += (int)bcnt[k];
        boff[c] = e;
        wcur[c] = (uint32_t)e;
    }
    if (t == 0) boff[CH] = np;
    __syncthreads();
    for (int i = t; i < np; i += 1024) {
        uint32_t p = plist[i];
        int x = (int)(p >> 13);
        uint32_t pos = atomicAdd(&wcur[x >> 3], 1u);
        bpts[pos] = (uint16_t)((((uint32_t)x & 7u) << 13) | (p & 0x1FFFu));
    }
}

// ---------------- K2: per-chunk column histogram + h-scan -> Dcol row ------
__global__ __launch_bounds__(256) void k_hrow(const uint16_t* __restrict__ bpts,
                                              const int* __restrict__ boff,
                                              int* __restrict__ Dcol) {
    __shared__ int H[HPAD];
    __shared__ int wsum[4];
    int c = blockIdx.x, t = threadIdx.x;
    for (int i = t; i < HPAD; i += 256) H[i] = 0;
    __syncthreads();
    int b0 = boff[c], b1 = boff[c + 1];
    for (int i = b0 + t; i < b1; i += 256) {
        uint32_t e = bpts[i];
        int y = (int)((e >> 1) & 0xFFFu);
        atomicAdd(&H[y + (y >> 4)], (e & 1u) ? 1 : -1);
    }
    __syncthreads();
    int base = t * 16;
    int v[16], s = 0;
    #pragma unroll
    for (int j = 0; j < 16; ++j) { s += H[17 * t + j]; v[j] = s; }
    int lane = t & 63, wid = t >> 6;
    int ss = s;
    #pragma unroll
    for (int d = 1; d < 64; d <<= 1) {
        int tmp = __shfl_up(ss, d);
        if (lane >= d) ss += tmp;
    }
    if (lane == 63) wsum[wid] = ss;
    __syncthreads();
    int carry = ss - s;
    #pragma unroll
    for (int w = 0; w < 4; ++w) if (w < wid) carry += wsum[w];
    int4* o = (int4*)(Dcol + (size_t)c * CPAD + base);
    #pragma unroll
    for (int q = 0; q < 4; ++q)
        o[q] = make_int4(v[4 * q + 0] + carry, v[4 * q + 1] + carry,
                         v[4 * q + 2] + carry, v[4 * q + 3] + carry);
}

// ---------------- K3a: strip sums of Dcol ---------------------------------
// SSD[s][col] = sum of Dcol rows in strip s.
__global__ __launch_bounds__(64) void k_vsA_D(const int* __restrict__ D,
                                              int* __restrict__ SSD) {
    int col = blockIdx.x * 64 + threadIdx.x;
    int s = blockIdx.y;
    int c0 = s * SSTR, c1 = min(CH, c0 + SSTR);
    int sum = 0;
    for (int c = c0; c < c1; ++c) sum += D[(size_t)c * CPAD + col];
    SSD[(size_t)s * CPAD + col] = sum;
}

// ---------------- K3b: exclusive apply -> Dcol becomes Hpre ----------------
// Hpre[c][y] = count of occ... = sum of Dcol rows < c (exclusive).
__global__ __launch_bounds__(64) void k_vsB_D(int* __restrict__ D,
                                              const int* __restrict__ SSD) {
    int col = blockIdx.x * 64 + threadIdx.x;
    int s = blockIdx.y;
    int run = 0;
    for (int k = 0; k < s; ++k) run += SSD[(size_t)k * CPAD + col];
    int c0 = s * SSTR, c1 = min(CH, c0 + SSTR);
    for (int c = c0; c < c1; ++c) {
        int tmp = D[(size_t)c * CPAD + col];
        D[(size_t)c * CPAD + col] = run;
        run += tmp;
    }
}

// ---------------- K4: occ build, one wave per (chunk, y-tile) --------------
__global__ __launch_bounds__(64) void k_occ(const uint16_t* __restrict__ bpts,
                                            const int* __restrict__ boff,
                                            const int* __restrict__ Hpre,
                                            uint32_t* __restrict__ occw,
                                            uint32_t* __restrict__ colsum32) {
    __shared__ int R[RPADL];
    __shared__ uint16_t loc[LOCCAP];
    __shared__ int carrD[RPC];
    __shared__ int nloc;
    int c = blockIdx.x;
    int tt = blockIdx.y;
    int r0 = c * RPC, y0 = tt * TW;
    int j = threadIdx.x;
    for (int i = j; i < RPADL; i += 64) R[i] = 0;
    if (j < RPC) carrD[j] = 0;
    if (j == 0) nloc = 0;
    __syncthreads();
    int b0 = boff[c], b1 = boff[c + 1];
    for (int i = b0 + j; i < b1; i += 64) {
        uint32_t e = bpts[i];
        int py = (int)((e >> 1) & 0xFFFu);
        int xr = (int)(e >> 13);
        int ry = py - y0;
        if (ry >= 0 && ry < TW) {
            int k = atomicAdd(&nloc, 1);
            if (k < LOCCAP)
                loc[k] = (uint16_t)((xr << 10) | (ry << 1) | (e & 1u));
        } else if (ry < 0) {
            atomicAdd(&carrD[xr], (e & 1u) ? 1 : -1);
        }
    }
    const int4* hp = (const int4*)(Hpre + (size_t)c * CPAD + y0 + j * 8);
    int4 h0 = hp[0], h1 = hp[1];
    int h[8] = {h0.x, h0.y, h0.z, h0.w, h1.x, h1.y, h1.z, h1.w};
    __syncthreads();
    bool ovf = (nloc > LOCCAP);
    int nl = ovf ? 0 : nloc;
    uint32_t cnt[8] = {0, 0, 0, 0, 0, 0, 0, 0};
    int cb = 0;
    int base = j * 8;
    for (int xr = 0; xr < RPC; ++xr) {
        if (!ovf) {
            for (int i = j; i < nl; i += 64) {
                uint32_t e = loc[i];
                if ((int)(e >> 10) == xr) {
                    int ry = (int)((e >> 1) & 0x1FFu);
                    atomicAdd(&R[ry + (ry >> 4)], (e & 1u) ? 1 : -1);
                }
            }
        } else {                 // correctness fallback: rescan this bucket
            for (int i = b0 + j; i < b1; i += 64) {
                uint32_t e = bpts[i];
                if ((int)(e >> 13) == xr) {
                    int ry = (int)((e >> 1) & 0xFFFu) - y0;
                    if (ry >= 0 && ry < TW)
                        atomicAdd(&R[ry + (ry >> 4)], (e & 1u) ? 1 : -1);
                }
            }
        }
        __syncthreads();
        cb += carrD[xr];
        int v[8], sl = 0;
        #pragma unroll
        for (int k = 0; k < 8; ++k) {
            int a = base + k;
            sl += R[a + (a >> 4)];
            v[k] = sl;
        }
        int ss = sl;
        #pragma unroll
        for (int d = 1; d < 64; d <<= 1) {
            int tmp = __shfl_up(ss, d);
            if (j >= d) ss += tmp;
        }
        int excl = ss - sl + cb;
        uint32_t m = 0;
        #pragma unroll
        for (int k = 0; k < 8; ++k) {
            int gy = y0 + base + k;
            if (gy < GN && (h[k] + excl + v[k]) > 0) m |= (1u << k);
        }
        #pragma unroll
        for (int k = 0; k < 8; ++k) cnt[k] += (m >> k) & 1u;
        uint32_t w = m << (8 * (j & 3));
        w |= __shfl_xor(w, 1);
        w |= __shfl_xor(w, 2);
        if ((j & 3) == 0)
            occw[(size_t)(r0 + xr) * OWS + tt * 16 + (j >> 2)] = w;
        __syncthreads();
    }
    uint4 cw;
    cw.x = cnt[0] | (cnt[1] << 16);
    cw.y = cnt[2] | (cnt[3] << 16);
    cw.z = cnt[4] | (cnt[5] << 16);
    cw.w = cnt[6] | (cnt[7] << 16);
    *(uint4*)(colsum32 + (((size_t)c * CPAD + y0 + base) >> 1)) = cw;
}

// ---------------- K5 fused: PO build (0..1001) + colsum strip sums ---------
// PO[x][w] = occ word | (exclusive word-popcount prefix << 48).
// SSC[s][w] = packed u16-pair sum of colsum over strip s (max 128/half, safe).
#define P16BLKS 1002
#define VSCBLKS 256          // 32 strips * 8 word-groups of 256
__global__ __launch_bounds__(256) void k_po_vsAC(const uint32_t* __restrict__ occw,
                                                 uint64_t* __restrict__ PO,
                                                 const uint32_t* __restrict__ colsum32,
                                                 uint32_t* __restrict__ SSC) {
    int blk = blockIdx.x;
    int t = threadIdx.x;
    if (blk < P16BLKS) {
        int lj = t & 63, wid = t >> 6;
        int x = blk * 4 + wid;
        uint2 w = ((const uint2*)(occw + (size_t)x * OWS))[lj];
        int p0 = __popc(w.x), p1 = __popc(w.y);
        int tot = p0 + p1;
        int ss = tot;
        #pragma unroll
        for (int d = 1; d < 64; d <<= 1) {
            int tmp = __shfl_up(ss, d);
            if (lj >= d) ss += tmp;
        }
        int excl = ss - tot;
        ulonglong2 o;
        o.x = (uint64_t)w.x | ((uint64_t)(uint32_t)excl << 48);
        o.y = (uint64_t)w.y | ((uint64_t)(uint32_t)(excl + p0) << 48);
        ((ulonglong2*)(PO + (size_t)x * PW))[lj] = o;
    } else {
        int b = blk - P16BLKS;
        int s = b >> 3;
        int w = (b & 7) * 256 + t;
        int c0 = s * SSTR, c1 = min(CH, c0 + SSTR);
        uint32_t sum = 0;
        for (int c = c0; c < c1; ++c) sum += colsum32[(size_t)c * (CPAD / 2) + w];
        SSC[(size_t)s * (CPAD / 2) + w] = sum;
    }
}

// ---------------- K6: exclusive strip apply -> Vc --------------------------
// Vc[c][y] = occ bits at col y in rows < 8c (exclusive over chunks); Vc[CH]=total.
__global__ __launch_bounds__(256) void k_vsB_C(const uint32_t* __restrict__ colsum32,
                                               const uint32_t* __restrict__ SSC,
                                               uint32_t* __restrict__ Vc32) {
    int b = blockIdx.x;
    int s = b >> 3;
    int w = (b & 7) * 256 + threadIdx.x;
    uint32_t run = 0;
    for (int k = 0; k < s; ++k) run += SSC[(size_t)k * (CPAD / 2) + w];
    int c0 = s * SSTR, c1 = min(CH, c0 + SSTR);
    for (int c = c0; c < c1; ++c) {
        Vc32[(size_t)c * (CPAD / 2) + w] = run;
        run += colsum32[(size_t)c * (CPAD / 2) + w];
    }
    if (c1 == CH) Vc32[(size_t)CH * (CPAD / 2) + w] = run;
}

// ---------------- K7: horizontal inclusive scan of Vc rows -> Ic -----------
__global__ __launch_bounds__(256) void k_hscanC(const uint16_t* __restrict__ Vc,
                                                int* __restrict__ Ic) {
    __shared__ int wsum[4];
    int c = blockIdx.x, t = threadIdx.x;
    const uint32_t* row = (const uint32_t*)(Vc + (size_t)c * CPAD);
    const int4* p = (const int4*)(row + (size_t)t * 8);
    int4 A = p[0];
    int4 B = p[1];
    uint32_t w[8] = {(uint32_t)A.x, (uint32_t)A.y, (uint32_t)A.z, (uint32_t)A.w,
                     (uint32_t)B.x, (uint32_t)B.y, (uint32_t)B.z, (uint32_t)B.w};
    int v[16], s = 0;
    #pragma unroll
    for (int q = 0; q < 8; ++q) {
        s += (int)(w[q] & 0xFFFFu); v[2 * q] = s;
        s += (int)(w[q] >> 16);     v[2 * q + 1] = s;
    }
    int lane = t & 63, wid = t >> 6;
    int ss = s;
    #pragma unroll
    for (int d = 1; d < 64; d <<= 1) {
        int tmp = __shfl_up(ss, d);
        if (lane >= d) ss += tmp;
    }
    if (lane == 63) wsum[wid] = ss;
    __syncthreads();
    int carry = ss - s;
    #pragma unroll
    for (int w2 = 0; w2 < 4; ++w2) if (w2 < wid) carry += wsum[w2];
    int4* o = (int4*)(Ic + (size_t)c * CPAD + (size_t)t * 16);
    #pragma unroll
    for (int q = 0; q < 4; ++q)
        o[q] = make_int4(v[4 * q + 0] + carry, v[4 * q + 1] + carry,
                         v[4 * q + 2] + carry, v[4 * q + 3] + carry);
}

// ---------------- K8: gather (thread per box-corner) + reduce + finalize ---
__device__ __forceinline__ int clampI(int a) {
    return a < 0 ? 0 : (a > GN ? GN : a);
}

__global__ __launch_bounds__(256) void k_gather(const float* __restrict__ pred, int npred,
                                                const int* __restrict__ Ic,
                                                const uint64_t* __restrict__ PO,
                                                double* __restrict__ acc,
                                                int* __restrict__ done,
                                                float* __restrict__ out, int nblocks) {
    __shared__ double red[4];
    int g = blockIdx.x * 256 + threadIdx.x;
    int i = g >> 2, k = g & 3;
    double l = 0.0;
    int x1 = 0, y1 = 0, x2 = 0, y2 = 0;
    int cov = 0;
    if (i < npred) {
        float4 bx = ((const float4*)pred)[i];
        x1 = (int)rintf(bx.x * 100.0f);
        y1 = (int)rintf(bx.y * 100.0f);
        x2 = (int)rintf(bx.z * 100.0f);
        y2 = (int)rintf(bx.w * 100.0f);
        int a1 = clampI(x1), b1 = clampI(y1), a2 = clampI(x2), b2 = clampI(y2);
        int a = (k & 1) ? a1 : a2;
        int b = (k & 2) ? b1 : b2;
        int sgn = ((k ^ (k >> 1)) & 1) ? -1 : 1;
        int Iv = 0;
        if (a > 0 && b > 0) {
            int c = a >> 3;
            Iv = Ic[(size_t)c * CPAD + (b - 1)];
            int bw = b >> 5;
            uint32_t mask = (1u << (b & 31)) - 1u;   // b&31==0 -> 0
            for (int x = (a & ~7); x < a; ++x) {
                uint64_t po = PO[(size_t)x * PW + bw];
                Iv += (int)(po >> 48) + __popc((uint32_t)po & mask);
            }
        }
        cov = sgn * Iv;
    }
    cov += __shfl_xor(cov, 1);
    cov += __shfl_xor(cov, 2);
    if (i < npred && k == 0) {
        int area = (x2 - x1) * (y2 - y1);
        bool valid = (x2 > x1) && (y2 > y1);
        float iou = valid ? ((float)cov / fmaxf((float)area, 1.0f)) : 0.0f;
        l = (double)(1.0f - iou);
    }
    #pragma unroll
    for (int d = 32; d > 0; d >>= 1) l += __shfl_down(l, d);
    int lane = threadIdx.x & 63, wid = threadIdx.x >> 6;
    if (lane == 0) red[wid] = l;
    __syncthreads();
    if (threadIdx.x == 0) {
        atomicAdd(acc, red[0] + red[1] + red[2] + red[3]);
        __threadfence();
        if (atomicAdd(done, 1) == nblocks - 1) {
            double total = atomicAdd(acc, 0.0);   // coherent read of final sum
            out[0] = (float)(total / (double)npred);
        }
    }
}

extern "C" void kernel_launch(void* const* d_in, const int* in_sizes, int n_in,
                              void* d_out, int out_size, void* d_ws, size_t ws_size,
                              hipStream_t stream) {
    const float* pred = (const float*)d_in[0];
    // d_in[1] = target, unused by the reference loss
    const float* gt = (const float*)d_in[2];
    int npred = in_sizes[0] / 4;
    int ngt = in_sizes[2] / 4;

    char* ws = (char*)d_ws;
    size_t off = 0;
    auto alloc = [&](size_t bytes) {
        void* p = ws + off;
        off = (off + bytes + 255) & ~(size_t)255;
        return p;
    };
    int* Dcol = (int*)alloc((size_t)CH * CPAD * sizeof(int));                  // 8.2 MB; becomes Hpre
    int* Ic = (int*)alloc((size_t)(CH + 1) * CPAD * sizeof(int));              // 8.2 MB
    uint32_t* occw = (uint32_t*)alloc((size_t)GN * OWS * sizeof(uint32_t));    // 2.05 MB
    uint64_t* PO = (uint64_t*)alloc((size_t)GN * PW * sizeof(uint64_t));       // 4.1 MB
    uint16_t* colsum = (uint16_t*)alloc((size_t)CH * CPAD * sizeof(uint16_t)); // 4.1 MB
    uint16_t* Vc = (uint16_t*)alloc((size_t)(CH + 1) * CPAD * sizeof(uint16_t)); // 4.1 MB
    int* SSD = (int*)alloc((size_t)NSTRIP * CPAD * sizeof(int));               // 512 KB
    uint32_t* SSC = (uint32_t*)alloc((size_t)NSTRIP * (CPAD / 2) * sizeof(uint32_t)); // 256 KB
    uint16_t* bpts = (uint16_t*)alloc((size_t)MAXPTS * sizeof(uint16_t));
    int* boff = (int*)alloc((size_t)(CH + 1) * sizeof(int));
    double* acc = (double*)alloc(sizeof(double));
    int* done = (int*)alloc(sizeof(int));

    int nb = (4 * npred + 255) / 256;
    k_points<<<dim3(1), dim3(1024), 0, stream>>>(gt, ngt, boff, bpts, acc, done);
    k_hrow<<<dim3(CH), dim3(256), 0, stream>>>(bpts, boff, Dcol);
    k_vsA_D<<<dim3(CPAD / 64, NSTRIP), dim3(64), 0, stream>>>(Dcol, SSD);
    k_vsB_D<<<dim3(CPAD / 64, NSTRIP), dim3(64), 0, stream>>>(Dcol, SSD);
    k_occ<<<dim3(CH, YT), dim3(64), 0, stream>>>(bpts, boff, Dcol, occw, (uint32_t*)colsum);
    k_po_vsAC<<<dim3(P16BLKS + VSCBLKS), dim3(256), 0, stream>>>(occw, PO,
                                                                 (const uint32_t*)colsum, SSC);
    k_vsB_C<<<dim3(VSCBLKS), dim3(256), 0, stream>>>((const uint32_t*)colsum, SSC, (uint32_t*)Vc);
    k_hscanC<<<dim3(CH + 1), dim3(256), 0, stream>>>(Vc, Ic);
    k_gather<<<dim3(nb), dim3(256), 0, stream>>>(pred, npred, Ic, PO, acc, done,
                                                 (float*)d_out, nb);
}